// Round 12
// baseline (229.157 us; speedup 1.0000x reference)
//
#include <hip/hip_runtime.h>
#include <hip/hip_fp16.h>
#include <math.h>

// SpinSphericalBlock: separable spin-weighted SHT -> channel mix -> inverse SHT
// -> complex BN (spin0 mean, via Parseval on G) -> magnitude-ReLU gating.
//
// Constants: B=8, RES=64, RES_OUT=32, L=15, SPINS_IN=(0,1), SPINS_OUT=(0,1,2),
// C_IN=64, C_OUT=128, NM=31. Output: out_size=3,145,728 float32 = Re(y),
// (b,t,p,s,d) row-major (established R0-R4).
//
// R28 = MEASUREMENT ROUND. Post-mortem R27: third structural attack on K3
// (traffic R18, chain+occupancy R27) all null at ~178-180us. Roofline model
// says K3 ~5-10us; R17 spill-arithmetic says ~65us; 13x contradiction that
// survived 3 falsifications -> one number is wrong and kernels have NEVER
// been directly observed (all below the 42us fill floor in top-5; K3's only
// direct measurement was R17's spill-poisoned 250us).
// Method: launch k_mix THREE times (idempotent: reads coeffs+W, writes oc
// deterministically, no atomics -> identical output).
//   dur_us - 178.3 = 2 x K3 (to +-1us).
//   If K3~65: dur~308 AND the extra k_mix dispatches surface in top-5 with
//             K3's first direct counters -> next round targets what they show.
//   If K3~10-15: dur~198-208 -> R17 inference was spill-contaminated; whale
//             is elsewhere (K1 fp64 tables / K5) -> duplicate K1 next.
// Pipeline otherwise byte-identical to R27 (178.3us verified).
//
//   K1 k_phi_tables: blocks<512: F[bt,m,iu] = sum_p x e^{-im phi_p} (radix-2)
//                    512..626: Wigner tables (fp64 recurrence) + zero stats
//                    627..674: pack weights into float4 W
//   K2 k_theta_in:   coeffs[b,k,iu]= sum_t A_in[i,k,t] F[b,t,m(k),iu]
//   K3 k_mix (x3):   oc[b,k,sd]    = sum_iu coeffs * W[l(k),i,s,u,d]
//   K4 k_theta_out:  G[bt,m,sd]    = sum_l A_out[s,k,t] oc[b,k,sd]  + stats
//   K5 k_synth_final: y = BN(sum_m G e^{+im phi'_p}) -> gate -> Re(y) (radix-2)

#define PI_D 3.14159265358979323846

// ---------------- workspace layout (bytes) ----------------
#define OFF_A_IN    ((size_t)24320)     // 2*256*64 float    = 131072
#define OFF_A_OUT   ((size_t)155648)    // 3*256*32 float    = 98304
#define OFF_STATS   ((size_t)254208)    // 3*384 float       = 4608
#define OFF_R1      ((size_t)260608)    // F fp16 (8.1MB) then oc fp16 (3.1MB)
#define OFF_R2      ((size_t)25426688)  // coeffs fp16 (1MB) then G fp16 (12.2MB)
#define OFF_W       ((size_t)67108864)  // packed weights float4 (6.3MB)

// ln(j!) for j=0..30
__constant__ double LF[31] = {
    0.0, 0.0, 0.6931471805599453, 1.791759469228055, 3.1780538303479458,
    4.787491742782046, 6.579251212010101, 8.525161361065415,
    10.604602902745251, 12.801827480081469, 15.104412573075516,
    17.502307845873887, 19.987214495661885, 22.552163853123425,
    25.19122118273868, 27.89927138384089, 30.671860106080672,
    33.50507345013689, 36.39544520803305, 39.339884187199495,
    42.335616460753485, 45.38013889847691, 48.47118135183523,
    51.60667556776438, 54.78472939811232, 58.00360522298052,
    61.261701761002, 64.55753862700634, 67.88974313718154,
    71.25703896716801, 74.65823634883016};

__device__ inline int isqrt_k(int k) {
    int l = (int)sqrtf((float)k + 0.5f);
    while (l * l > k) --l;
    while ((l + 1) * (l + 1) <= k) ++l;
    return l;
}

// d^l_{m,n}(theta) via seed term (1 exp + 2 log) + exact ratio recurrence.
__device__ double wigner_d_rec(int l, int m, int n, double theta) {
    int an = n < 0 ? -n : n;
    int am = m < 0 ? -m : m;
    if (l < an || l < am) return 0.0;
    int kmin = max(0, n - m), kmax = min(l + n, l - m);
    if (kmax < kmin) return 0.0;
    double cb = cos(0.5 * theta), sb = sin(0.5 * theta);
    double pref = 0.5 * (LF[l + m] + LF[l - m] + LF[l + n] + LF[l - n]);
    double lterm = pref
        - (LF[l + n - kmin] + LF[kmin] + LF[m - n + kmin] + LF[l - m - kmin])
        + (double)(2 * l + n - m - 2 * kmin) * log(cb)
        + (double)(m - n + 2 * kmin) * log(sb);
    double term = exp(lterm);
    if ((m - n + kmin) & 1) term = -term;
    double r = (sb * sb) / (cb * cb);
    double acc = term;
    for (int k = kmin; k < kmax; ++k) {
        term *= -((double)((l + n - k) * (l - m - k)) * r)
                / ((double)((k + 1) * (m - n + k + 1)));
        acc += term;
    }
    return acc;
}

// K1: fused phi-DFT (blocks 0..511) + table generation (512..626)
//     + weight packing (627..674).
__global__ __launch_bounds__(512, 2) void k_phi_tables(const float* __restrict__ xr,
                                                       const float* __restrict__ xi,
                                                       __half2* __restrict__ F,
                                                       float* __restrict__ A_in,
                                                       float* __restrict__ A_out,
                                                       float* __restrict__ stats,
                                                       const float* __restrict__ kr,
                                                       const float* __restrict__ ki,
                                                       float4* __restrict__ W) {
    if (blockIdx.x >= 512) {
        if (blockIdx.x >= 627) {
            // pack kr/ki -> W[lis][u][dp] = (kr2d, kr2d+1, ki2d, ki2d+1)
            int e0 = (blockIdx.x - 627) * 512 + threadIdx.x;
            const float2* kr2 = (const float2*)kr;
            const float2* ki2 = (const float2*)ki;
#pragma unroll
            for (int j = 0; j < 16; ++j) {
                int e = e0 + j * 24576;
                int dp = e & 63, r = e >> 6;   // r = lis*64 + u, r < 6144
                float2 a = kr2[(size_t)r * 64 + dp];
                float2 b = ki2[(size_t)r * 64 + dp];
                W[e] = make_float4(a.x, a.y, b.x, b.y);
            }
            return;
        }
        int idx = (blockIdx.x - 512) * 512 + threadIdx.x;
        if (idx < 32768) {
            int t = idx & 63, k = (idx >> 6) & 255, i = idx >> 14;
            int l = isqrt_k(k);
            int m = k - l * l - l;
            double theta = ((double)t + 0.5) * PI_D / 64.0;
            double w = sin(theta) * (PI_D / 64.0) * (2.0 * PI_D / 64.0);
            double norm = sqrt((2.0 * l + 1.0) / (4.0 * PI_D));
            double d = wigner_d_rec(l, m, -i, theta);
            A_in[idx] = (float)(((m & 1) ? -1.0 : 1.0) * norm * w * d);
            return;
        }
        idx -= 32768;
        if (idx < 24576) {
            int t = idx & 31, k = (idx >> 5) & 255, s = idx >> 13;
            int l = isqrt_k(k);
            int m = k - l * l - l;
            double theta = ((double)t + 0.5) * PI_D / 32.0;
            double norm = sqrt((2.0 * l + 1.0) / (4.0 * PI_D));
            double d = wigner_d_rec(l, m, -s, theta);
            A_out[idx] = (float)(((m & 1) ? -1.0 : 1.0) * norm * d);
            return;
        }
        idx -= 24576;
        if (idx < 1152) stats[idx] = 0.f;
        return;
    }
    int bt = blockIdx.x;
    int iu = threadIdx.x & 127, mh = threadIdx.x >> 7;
    int mi0 = mh * 8;
    float2 acc[8], w[8], st[8];
#pragma unroll
    for (int j = 0; j < 8; ++j) {
        int m = mi0 + j - 15;
        float sy, sx;
        __sincosf(-(float)m * (float)(PI_D / 32.0), &sy, &sx);
        st[j] = make_float2(sx, sy);
        w[j] = make_float2(1.f, 0.f);
        acc[j] = make_float2(0.f, 0.f);
    }
    const float* xrb = xr + (size_t)bt * 8192 + iu;
    const float* xib = xi + (size_t)bt * 8192 + iu;
    for (int p = 0; p < 32; ++p) {
        float a  = xrb[(size_t)p * 128];
        float b  = xib[(size_t)p * 128];
        float a2 = xrb[(size_t)(p + 32) * 128];
        float b2 = xib[(size_t)(p + 32) * 128];
        float sar = a + a2, sai = b + b2;   // for even m
        float dar = a - a2, dai = b - b2;   // for odd m
#pragma unroll
        for (int j = 0; j < 8; ++j) {
            float ur = (j & 1) ? sar : dar;  // j odd -> m even
            float ui = (j & 1) ? sai : dai;
            acc[j].x += ur * w[j].x - ui * w[j].y;
            acc[j].y += ur * w[j].y + ui * w[j].x;
            float nx = w[j].x * st[j].x - w[j].y * st[j].y;
            w[j].y = w[j].x * st[j].y + w[j].y * st[j].x;
            w[j].x = nx;
        }
    }
    __half2* Fb = F + (size_t)bt * 31 * 128 + iu;
#pragma unroll
    for (int j = 0; j < 8; ++j) {
        int mi = mi0 + j;
        if (mi < 31) Fb[(size_t)mi * 128] = __float22half2_rn(acc[j]);
    }
}

// K2: theta contraction. grid (31, 8, 2) = (mi, b, iu-half); 256 threads =
// (iu_l 64) x (th 4). iu-half == spin index i, so only one A_in plane staged.
__global__ __launch_bounds__(256, 4) void k_theta_in(const __half2* __restrict__ F,
                                                     const float* __restrict__ A_in,
                                                     __half2* __restrict__ coeffs) {
    __shared__ float A[16][64];        // 4 KB, zero-padded below |m|
    __shared__ float2 red[2][16][64];  // 16 KB reduction buffer
    int mi = blockIdx.x, b = blockIdx.y, z = blockIdx.z;  // z = i
    int m = mi - 15;
    int am = m < 0 ? -m : m;
    int tid = threadIdx.x;
    for (int idx = tid; idx < 1024; idx += 256) {
        int j = idx >> 6, t = idx & 63;
        float v = 0.f;
        if (j >= am) v = A_in[((size_t)z * 256 + (j * j + j + m)) * 64 + t];
        A[j][t] = v;
    }
    __syncthreads();
    int iu_l = tid & 63, th = tid >> 6;
    int iu = z * 64 + iu_l;
    float2 acc[16];
#pragma unroll
    for (int j = 0; j < 16; ++j) acc[j] = make_float2(0.f, 0.f);
    const __half2* Fb = F + ((size_t)b * 64 * 31 + mi) * 128 + iu;
    for (int tt = 0; tt < 16; ++tt) {
        int t = th * 16 + tt;
        float2 f = __half22float2(Fb[(size_t)t * 31 * 128]);
#pragma unroll
        for (int j = 0; j < 16; ++j) {
            float a = A[j][t];
            acc[j].x += a * f.x;
            acc[j].y += a * f.y;
        }
    }
    if (th >= 2) {
#pragma unroll
        for (int j = 0; j < 16; ++j) red[th - 2][j][iu_l] = acc[j];
    }
    __syncthreads();
    if (th < 2) {
#pragma unroll
        for (int j = 0; j < 16; ++j) {
            float2 r = red[th][j][iu_l];
            acc[j].x += r.x;
            acc[j].y += r.y;
        }
    }
    __syncthreads();
    if (th == 1) {
#pragma unroll
        for (int j = 0; j < 16; ++j) red[0][j][iu_l] = acc[j];
    }
    __syncthreads();
    if (th == 0) {
#pragma unroll
        for (int j = 0; j < 16; ++j) {
            if (j >= am) {
                float2 r = red[0][j][iu_l];
                coeffs[((size_t)b * 256 + (j * j + j + m)) * 128 + iu] =
                    __float22half2_rn(make_float2(acc[j].x + r.x, acc[j].y + r.y));
            }
        }
    }
}

// K3: channel mix, i-split (R27 form). grid (256, 2); 384 thr = (ih,s,dp).
// IDEMPOTENT: reads coeffs+W, writes oc deterministically -> safe to repeat.
__global__ __launch_bounds__(384) void k_mix(const __half2* __restrict__ coeffs,
                                             const float4* __restrict__ W,
                                             __half2* __restrict__ oc) {
    __shared__ float2 cs[4][128];      // 4 KB
    __shared__ float2 red[192][4][2];  // 12 KB
    int bx = blockIdx.x;
    int k = ((bx & 7) << 5) + (bx >> 3);  // XCD-chunked k
    int b0 = blockIdx.y * 4;
    int tid = threadIdx.x;
    for (int idx = tid; idx < 512; idx += 384) {
        int bb = idx >> 7, iuu = idx & 127;
        cs[bb][iuu] =
            __half22float2(coeffs[((size_t)(b0 + bb) * 256 + k) * 128 + iuu]);
    }
    __syncthreads();
    int ih = tid >= 192 ? 1 : 0;
    int r = tid - ih * 192;
    int s = r >> 6, dp = r & 63;
    int l = isqrt_k(k);
    float2 acc[4][2];
#pragma unroll
    for (int bb = 0; bb < 4; ++bb) {
        acc[bb][0] = make_float2(0.f, 0.f);
        acc[bb][1] = make_float2(0.f, 0.f);
    }
    const float4* Wb = W + (size_t)(6 * l + 3 * ih + s) * 4096 + dp;
    float4 cur[4];
#pragma unroll
    for (int j = 0; j < 4; ++j) cur[j] = Wb[(size_t)j * 64];
    for (int g = 0; g < 16; ++g) {
        float4 nxt[4];
        if (g < 15) {
#pragma unroll
            for (int j = 0; j < 4; ++j)
                nxt[j] = Wb[(size_t)((g + 1) * 4 + j) * 64];
        }
#pragma unroll
        for (int j = 0; j < 4; ++j) {
            int iu = ih * 64 + g * 4 + j;
            float2 wr = make_float2(cur[j].x, cur[j].y);
            float2 wi = make_float2(cur[j].z, cur[j].w);
#pragma unroll
            for (int bb = 0; bb < 4; ++bb) {
                float2 cv = cs[bb][iu];
                acc[bb][0].x += cv.x * wr.x - cv.y * wi.x;
                acc[bb][0].y += cv.x * wi.x + cv.y * wr.x;
                acc[bb][1].x += cv.x * wr.y - cv.y * wi.y;
                acc[bb][1].y += cv.x * wi.y + cv.y * wr.y;
            }
        }
        if (g < 15) {
#pragma unroll
            for (int j = 0; j < 4; ++j) cur[j] = nxt[j];
        }
    }
    if (ih == 1) {
#pragma unroll
        for (int bb = 0; bb < 4; ++bb) {
            red[r][bb][0] = acc[bb][0];
            red[r][bb][1] = acc[bb][1];
        }
    }
    __syncthreads();
    if (ih == 0) {
#pragma unroll
        for (int bb = 0; bb < 4; ++bb) {
            float2 r0 = red[r][bb][0];
            float2 r1 = red[r][bb][1];
            size_t o = ((size_t)(b0 + bb) * 256 + k) * 384 + s * 128 + 2 * dp;
            oc[o]     = __float22half2_rn(
                make_float2(acc[bb][0].x + r0.x, acc[bb][0].y + r0.y));
            oc[o + 1] = __float22half2_rn(
                make_float2(acc[bb][1].x + r1.x, acc[bb][1].y + r1.y));
        }
    }
}

// K4: theta expansion + stats. grid (31, 8, 2) = (mi, b, sd-half); 192 threads.
__global__ __launch_bounds__(192, 4) void k_theta_out(const __half2* __restrict__ oc,
                                                      const float* __restrict__ A_out,
                                                      __half2* __restrict__ G,
                                                      float* __restrict__ ssr,
                                                      float* __restrict__ ssi,
                                                      float* __restrict__ ssq) {
    __shared__ float Ao[3][16][32];  // 6KB
    int mi = blockIdx.x, b = blockIdx.y, z = blockIdx.z;
    int m = mi - 15;
    int am = m < 0 ? -m : m;
    int tid = threadIdx.x;
    for (int idx = tid; idx < 1536; idx += 192) {
        int s = idx >> 9, j = (idx >> 5) & 15, t = idx & 31;
        float v = 0.f;
        if (j >= am) v = A_out[((size_t)s * 256 + (j * j + j + m)) * 32 + t];
        Ao[s][j][t] = v;
    }
    __syncthreads();
    int sd = z * 192 + tid;
    int s = sd >> 7;
    float2 c[16];
#pragma unroll
    for (int j = 0; j < 16; ++j) {
        c[j] = make_float2(0.f, 0.f);
        if (j >= am)
            c[j] = __half22float2(oc[((size_t)b * 256 + (j * j + j + m)) * 384 + sd]);
    }
    float sq = 0.f, sr = 0.f, si = 0.f;
    for (int t = 0; t < 32; ++t) {
        float fr = 0.f, fi = 0.f;
#pragma unroll
        for (int j = 0; j < 16; ++j) {
            float a = Ao[s][j][t];
            fr += a * c[j].x;
            fi += a * c[j].y;
        }
        G[(((size_t)b * 32 + t) * 31 + mi) * 384 + sd] =
            __float22half2_rn(make_float2(fr, fi));
        sq += fr * fr + fi * fi;
        if (mi == 15) { sr += fr; si += fi; }
    }
    atomicAdd(&ssq[sd], sq);
    if (mi == 15) {
        atomicAdd(&ssr[sd], sr);
        atomicAdd(&ssi[sd], si);
    }
}

// K5: phi synthesis + BN + gate, radix-2 folded. grid (256 bt, 2 sd-half),
// 192 threads. Rotation state (g[31]+st[31]) in registers; (192,2) caps 256.
__global__ __launch_bounds__(192, 2) void k_synth_final(const __half2* __restrict__ G,
                                                        const float* __restrict__ ssr,
                                                        const float* __restrict__ ssi,
                                                        const float* __restrict__ ssq,
                                                        const float* __restrict__ gamma,
                                                        const float* __restrict__ betar,
                                                        const float* __restrict__ betai,
                                                        const float* __restrict__ bias,
                                                        float* __restrict__ out) {
    int bt = blockIdx.x;
    int sd = blockIdx.y * 192 + threadIdx.x;
    int s = sd >> 7;
    float2 g[31], st[31];
#pragma unroll
    for (int mi = 0; mi < 31; ++mi) {
        g[mi] = __half22float2(G[((size_t)bt * 31 + mi) * 384 + sd]);
        float sy, sx;
        __sincosf((float)(mi - 15) * (float)(PI_D / 16.0), &sy, &sx);
        st[mi] = make_float2(sx, sy);
    }
    const float invN = 1.0f / 256.0f;
    float mur = 0.f, mui = 0.f;
    if (s == 0) { mur = ssr[sd] * invN; mui = ssi[sd] * invN; }
    float var = ssq[sd] * invN - (mur * mur + mui * mui);
    float scale = gamma[sd] / sqrtf(var + 1e-5f);
    float br = (s == 0) ? betar[sd] : 0.f;
    float bi = (s == 0) ? betai[sd] : 0.f;
    float bb = bias[sd];
    float* ob = out + (size_t)bt * 32 * 384 + sd;
    for (int p = 0; p < 16; ++p) {
        float fr = 0.f, fi = 0.f, fr2 = 0.f, fi2 = 0.f;
#pragma unroll
        for (int mi = 0; mi < 31; ++mi) {
            fr += g[mi].x;
            fi += g[mi].y;
            if (mi & 1) { fr2 += g[mi].x; fi2 += g[mi].y; }  // m even
            else        { fr2 -= g[mi].x; fi2 -= g[mi].y; }  // m odd
        }
        {
            float yr = (fr - mur) * scale + br;
            float yi = (fi - mui) * scale + bi;
            float mag = sqrtf(yr * yr + yi * yi);
            float f = fmaxf(mag + bb, 0.f) / (mag + 1e-6f);
            ob[(size_t)p * 384] = yr * f;
        }
        {
            float yr = (fr2 - mur) * scale + br;
            float yi = (fi2 - mui) * scale + bi;
            float mag = sqrtf(yr * yr + yi * yi);
            float f = fmaxf(mag + bb, 0.f) / (mag + 1e-6f);
            ob[(size_t)(p + 16) * 384] = yr * f;
        }
#pragma unroll
        for (int mi = 0; mi < 31; ++mi) {
            float nx = g[mi].x * st[mi].x - g[mi].y * st[mi].y;
            g[mi].y = g[mi].x * st[mi].y + g[mi].y * st[mi].x;
            g[mi].x = nx;
        }
    }
}

extern "C" void kernel_launch(void* const* d_in, const int* in_sizes, int n_in,
                              void* d_out, int out_size, void* d_ws, size_t ws_size,
                              hipStream_t stream) {
    const float* xr    = (const float*)d_in[0];
    const float* xi    = (const float*)d_in[1];
    const float* kr    = (const float*)d_in[2];
    const float* ki    = (const float*)d_in[3];
    const float* gamma = (const float*)d_in[4];
    const float* betar = (const float*)d_in[5];
    const float* betai = (const float*)d_in[6];
    const float* bias  = (const float*)d_in[7];
    float* out = (float*)d_out;

    char* ws = (char*)d_ws;
    float*   A_in   = (float*)(ws + OFF_A_IN);
    float*   A_out  = (float*)(ws + OFF_A_OUT);
    float*   stats  = (float*)(ws + OFF_STATS);
    float*   ssr    = stats;
    float*   ssi    = stats + 384;
    float*   ssq    = stats + 768;
    __half2* F      = (__half2*)(ws + OFF_R1);  // then oc (fp16)
    __half2* oc     = (__half2*)(ws + OFF_R1);
    __half2* coeffs = (__half2*)(ws + OFF_R2);  // then G (fp16)
    __half2* G      = (__half2*)(ws + OFF_R2);
    float4*  W      = (float4*)(ws + OFF_W);

    k_phi_tables<<<675, 512, 0, stream>>>(xr, xi, F, A_in, A_out, stats, kr, ki, W);
    k_theta_in<<<dim3(31, 8, 2), 256, 0, stream>>>(F, A_in, coeffs);
    // MEASUREMENT: k_mix x3 (idempotent). dur_us - 178.3 = 2 x K3.
    k_mix<<<dim3(256, 2), 384, 0, stream>>>(coeffs, W, oc);
    k_mix<<<dim3(256, 2), 384, 0, stream>>>(coeffs, W, oc);
    k_mix<<<dim3(256, 2), 384, 0, stream>>>(coeffs, W, oc);
    k_theta_out<<<dim3(31, 8, 2), 192, 0, stream>>>(oc, A_out, G, ssr, ssi, ssq);
    k_synth_final<<<dim3(256, 2), 192, 0, stream>>>(G, ssr, ssi, ssq,
                                                    gamma, betar, betai, bias, out);
}

// Round 13
// 177.666 us; speedup vs baseline: 1.2898x; 1.2898x over previous
//
#include <hip/hip_runtime.h>
#include <hip/hip_fp16.h>
#include <math.h>

// SpinSphericalBlock: separable spin-weighted SHT -> channel mix -> inverse SHT
// -> complex BN (spin0 mean, via Parseval on G) -> magnitude-ReLU gating.
//
// Constants: B=8, RES=64, RES_OUT=32, L=15, SPINS_IN=(0,1), SPINS_OUT=(0,1,2),
// C_IN=64, C_OUT=128, NM=31. Output: out_size=3,145,728 float32 = Re(y),
// (b,t,p,s,d) row-major (established R0-R4).
//
// R29 post-mortem of R28 (measurement): K3-repeat = 25.4us (dur delta 50.9/2)
// but in-pipeline K3 = ~65us (R17 arithmetic, solid). Both measured -> first
// run pays ~40us extra on 7.3MB of just-written inputs (~180 GB/s) = the
// signature of CROSS-XCD DIRTY-LINE SERVICING: producer stores sit dirty in
// the writer-XCD's private L2; consumers on other XCDs pull each line through
// the coherence path. Explains EVERY null so far (R15/R18/R27 never touched
// the handoff; mega paid it internally). Total handoff: F 8.1 + W 6.3 +
// coeffs 1 + oc 3.1 + G 12.2 ~= 30.7MB/iter ~= the ~85us gap between compute
// models (~50us) and measured kernel time (~136us).
// Fix: NON-TEMPORAL stores for all intermediates + nt loads for single-use
// reads (streaming/evict-first -> lines land clean at LLC, not dirty in L2).
// W reads stay cached (legit cross-k reuse of now-clean lines).
// Pipeline structure byte-identical to R27 (178.3us proven); k_mix x1.
//
//   K1 k_phi_tables: blocks<512: F[bt,m,iu] = sum_p x e^{-im phi_p} (radix-2)
//                    512..626: Wigner tables (fp64 recurrence) + zero stats
//                    627..674: pack weights into float4 W
//   K2 k_theta_in:   coeffs[b,k,iu]= sum_t A_in[i,k,t] F[b,t,m(k),iu]
//   K3 k_mix:        oc[b,k,sd]    = sum_iu coeffs * W[l(k),i,s,u,d]
//   K4 k_theta_out:  G[bt,m,sd]    = sum_l A_out[s,k,t] oc[b,k,sd]  + stats
//   K5 k_synth_final: y = BN(sum_m G e^{+im phi'_p}) -> gate -> Re(y) (radix-2)

#define PI_D 3.14159265358979323846

// ---------------- workspace layout (bytes) ----------------
#define OFF_A_IN    ((size_t)24320)     // 2*256*64 float    = 131072
#define OFF_A_OUT   ((size_t)155648)    // 3*256*32 float    = 98304
#define OFF_STATS   ((size_t)254208)    // 3*384 float       = 4608
#define OFF_R1      ((size_t)260608)    // F fp16 (8.1MB) then oc fp16 (3.1MB)
#define OFF_R2      ((size_t)25426688)  // coeffs fp16 (1MB) then G fp16 (12.2MB)
#define OFF_W       ((size_t)67108864)  // packed weights float4 (6.3MB)

// ---- non-temporal access helpers (cache-policy hints only) ----
typedef float f4ev __attribute__((ext_vector_type(4)));

__device__ __forceinline__ void nts_h2(__half2* p, __half2 v) {
    union { __half2 h; unsigned u; } c;
    c.h = v;
    __builtin_nontemporal_store(c.u, (unsigned*)p);
}
__device__ __forceinline__ __half2 ntl_h2(const __half2* p) {
    union { unsigned u; __half2 h; } c;
    c.u = __builtin_nontemporal_load((unsigned*)p);
    return c.h;
}
__device__ __forceinline__ void nts_f4(float4* p, float a, float b, float c,
                                       float d) {
    f4ev t;
    t.x = a; t.y = b; t.z = c; t.w = d;
    __builtin_nontemporal_store(t, (f4ev*)p);
}
__device__ __forceinline__ void nts_f(float* p, float v) {
    __builtin_nontemporal_store(v, p);
}

// ln(j!) for j=0..30
__constant__ double LF[31] = {
    0.0, 0.0, 0.6931471805599453, 1.791759469228055, 3.1780538303479458,
    4.787491742782046, 6.579251212010101, 8.525161361065415,
    10.604602902745251, 12.801827480081469, 15.104412573075516,
    17.502307845873887, 19.987214495661885, 22.552163853123425,
    25.19122118273868, 27.89927138384089, 30.671860106080672,
    33.50507345013689, 36.39544520803305, 39.339884187199495,
    42.335616460753485, 45.38013889847691, 48.47118135183523,
    51.60667556776438, 54.78472939811232, 58.00360522298052,
    61.261701761002, 64.55753862700634, 67.88974313718154,
    71.25703896716801, 74.65823634883016};

__device__ inline int isqrt_k(int k) {
    int l = (int)sqrtf((float)k + 0.5f);
    while (l * l > k) --l;
    while ((l + 1) * (l + 1) <= k) ++l;
    return l;
}

// d^l_{m,n}(theta) via seed term (1 exp + 2 log) + exact ratio recurrence.
__device__ double wigner_d_rec(int l, int m, int n, double theta) {
    int an = n < 0 ? -n : n;
    int am = m < 0 ? -m : m;
    if (l < an || l < am) return 0.0;
    int kmin = max(0, n - m), kmax = min(l + n, l - m);
    if (kmax < kmin) return 0.0;
    double cb = cos(0.5 * theta), sb = sin(0.5 * theta);
    double pref = 0.5 * (LF[l + m] + LF[l - m] + LF[l + n] + LF[l - n]);
    double lterm = pref
        - (LF[l + n - kmin] + LF[kmin] + LF[m - n + kmin] + LF[l - m - kmin])
        + (double)(2 * l + n - m - 2 * kmin) * log(cb)
        + (double)(m - n + 2 * kmin) * log(sb);
    double term = exp(lterm);
    if ((m - n + kmin) & 1) term = -term;
    double r = (sb * sb) / (cb * cb);
    double acc = term;
    for (int k = kmin; k < kmax; ++k) {
        term *= -((double)((l + n - k) * (l - m - k)) * r)
                / ((double)((k + 1) * (m - n + k + 1)));
        acc += term;
    }
    return acc;
}

// K1: fused phi-DFT (blocks 0..511) + table generation (512..626)
//     + weight packing (627..674). Intermediate stores: non-temporal.
__global__ __launch_bounds__(512, 2) void k_phi_tables(const float* __restrict__ xr,
                                                       const float* __restrict__ xi,
                                                       __half2* __restrict__ F,
                                                       float* __restrict__ A_in,
                                                       float* __restrict__ A_out,
                                                       float* __restrict__ stats,
                                                       const float* __restrict__ kr,
                                                       const float* __restrict__ ki,
                                                       float4* __restrict__ W) {
    if (blockIdx.x >= 512) {
        if (blockIdx.x >= 627) {
            // pack kr/ki -> W[lis][u][dp] = (kr2d, kr2d+1, ki2d, ki2d+1)
            int e0 = (blockIdx.x - 627) * 512 + threadIdx.x;
            const float2* kr2 = (const float2*)kr;
            const float2* ki2 = (const float2*)ki;
#pragma unroll
            for (int j = 0; j < 16; ++j) {
                int e = e0 + j * 24576;
                int dp = e & 63, r = e >> 6;   // r = lis*64 + u, r < 6144
                float2 a = kr2[(size_t)r * 64 + dp];
                float2 b = ki2[(size_t)r * 64 + dp];
                nts_f4(&W[e], a.x, a.y, b.x, b.y);
            }
            return;
        }
        int idx = (blockIdx.x - 512) * 512 + threadIdx.x;
        if (idx < 32768) {
            int t = idx & 63, k = (idx >> 6) & 255, i = idx >> 14;
            int l = isqrt_k(k);
            int m = k - l * l - l;
            double theta = ((double)t + 0.5) * PI_D / 64.0;
            double w = sin(theta) * (PI_D / 64.0) * (2.0 * PI_D / 64.0);
            double norm = sqrt((2.0 * l + 1.0) / (4.0 * PI_D));
            double d = wigner_d_rec(l, m, -i, theta);
            A_in[idx] = (float)(((m & 1) ? -1.0 : 1.0) * norm * w * d);
            return;
        }
        idx -= 32768;
        if (idx < 24576) {
            int t = idx & 31, k = (idx >> 5) & 255, s = idx >> 13;
            int l = isqrt_k(k);
            int m = k - l * l - l;
            double theta = ((double)t + 0.5) * PI_D / 32.0;
            double norm = sqrt((2.0 * l + 1.0) / (4.0 * PI_D));
            double d = wigner_d_rec(l, m, -s, theta);
            A_out[idx] = (float)(((m & 1) ? -1.0 : 1.0) * norm * d);
            return;
        }
        idx -= 24576;
        if (idx < 1152) stats[idx] = 0.f;
        return;
    }
    int bt = blockIdx.x;
    int iu = threadIdx.x & 127, mh = threadIdx.x >> 7;
    int mi0 = mh * 8;
    float2 acc[8], w[8], st[8];
#pragma unroll
    for (int j = 0; j < 8; ++j) {
        int m = mi0 + j - 15;
        float sy, sx;
        __sincosf(-(float)m * (float)(PI_D / 32.0), &sy, &sx);
        st[j] = make_float2(sx, sy);
        w[j] = make_float2(1.f, 0.f);
        acc[j] = make_float2(0.f, 0.f);
    }
    const float* xrb = xr + (size_t)bt * 8192 + iu;
    const float* xib = xi + (size_t)bt * 8192 + iu;
    for (int p = 0; p < 32; ++p) {
        float a  = xrb[(size_t)p * 128];
        float b  = xib[(size_t)p * 128];
        float a2 = xrb[(size_t)(p + 32) * 128];
        float b2 = xib[(size_t)(p + 32) * 128];
        float sar = a + a2, sai = b + b2;   // for even m
        float dar = a - a2, dai = b - b2;   // for odd m
#pragma unroll
        for (int j = 0; j < 8; ++j) {
            float ur = (j & 1) ? sar : dar;  // j odd -> m even
            float ui = (j & 1) ? sai : dai;
            acc[j].x += ur * w[j].x - ui * w[j].y;
            acc[j].y += ur * w[j].y + ui * w[j].x;
            float nx = w[j].x * st[j].x - w[j].y * st[j].y;
            w[j].y = w[j].x * st[j].y + w[j].y * st[j].x;
            w[j].x = nx;
        }
    }
    __half2* Fb = F + (size_t)bt * 31 * 128 + iu;
#pragma unroll
    for (int j = 0; j < 8; ++j) {
        int mi = mi0 + j;
        if (mi < 31) nts_h2(&Fb[(size_t)mi * 128], __float22half2_rn(acc[j]));
    }
}

// K2: theta contraction. grid (31, 8, 2) = (mi, b, iu-half); 256 threads.
// F loads nt (single-use); coeffs stores nt.
__global__ __launch_bounds__(256, 4) void k_theta_in(const __half2* __restrict__ F,
                                                     const float* __restrict__ A_in,
                                                     __half2* __restrict__ coeffs) {
    __shared__ float A[16][64];        // 4 KB, zero-padded below |m|
    __shared__ float2 red[2][16][64];  // 16 KB reduction buffer
    int mi = blockIdx.x, b = blockIdx.y, z = blockIdx.z;  // z = i
    int m = mi - 15;
    int am = m < 0 ? -m : m;
    int tid = threadIdx.x;
    for (int idx = tid; idx < 1024; idx += 256) {
        int j = idx >> 6, t = idx & 63;
        float v = 0.f;
        if (j >= am) v = A_in[((size_t)z * 256 + (j * j + j + m)) * 64 + t];
        A[j][t] = v;
    }
    __syncthreads();
    int iu_l = tid & 63, th = tid >> 6;
    int iu = z * 64 + iu_l;
    float2 acc[16];
#pragma unroll
    for (int j = 0; j < 16; ++j) acc[j] = make_float2(0.f, 0.f);
    const __half2* Fb = F + ((size_t)b * 64 * 31 + mi) * 128 + iu;
    for (int tt = 0; tt < 16; ++tt) {
        int t = th * 16 + tt;
        float2 f = __half22float2(ntl_h2(&Fb[(size_t)t * 31 * 128]));
#pragma unroll
        for (int j = 0; j < 16; ++j) {
            float a = A[j][t];
            acc[j].x += a * f.x;
            acc[j].y += a * f.y;
        }
    }
    if (th >= 2) {
#pragma unroll
        for (int j = 0; j < 16; ++j) red[th - 2][j][iu_l] = acc[j];
    }
    __syncthreads();
    if (th < 2) {
#pragma unroll
        for (int j = 0; j < 16; ++j) {
            float2 r = red[th][j][iu_l];
            acc[j].x += r.x;
            acc[j].y += r.y;
        }
    }
    __syncthreads();
    if (th == 1) {
#pragma unroll
        for (int j = 0; j < 16; ++j) red[0][j][iu_l] = acc[j];
    }
    __syncthreads();
    if (th == 0) {
#pragma unroll
        for (int j = 0; j < 16; ++j) {
            if (j >= am) {
                float2 r = red[0][j][iu_l];
                nts_h2(&coeffs[((size_t)b * 256 + (j * j + j + m)) * 128 + iu],
                       __float22half2_rn(
                           make_float2(acc[j].x + r.x, acc[j].y + r.y)));
            }
        }
    }
}

// K3: channel mix, i-split (R27 form). grid (256, 2); 384 thr = (ih,s,dp).
// coeffs staged via nt loads; W reads cached (cross-k reuse of clean lines);
// oc stores nt.
__global__ __launch_bounds__(384) void k_mix(const __half2* __restrict__ coeffs,
                                             const float4* __restrict__ W,
                                             __half2* __restrict__ oc) {
    __shared__ float2 cs[4][128];      // 4 KB
    __shared__ float2 red[192][4][2];  // 12 KB
    int bx = blockIdx.x;
    int k = ((bx & 7) << 5) + (bx >> 3);  // XCD-chunked k
    int b0 = blockIdx.y * 4;
    int tid = threadIdx.x;
    for (int idx = tid; idx < 512; idx += 384) {
        int bb = idx >> 7, iuu = idx & 127;
        cs[bb][iuu] = __half22float2(
            ntl_h2(&coeffs[((size_t)(b0 + bb) * 256 + k) * 128 + iuu]));
    }
    __syncthreads();
    int ih = tid >= 192 ? 1 : 0;
    int r = tid - ih * 192;
    int s = r >> 6, dp = r & 63;
    int l = isqrt_k(k);
    float2 acc[4][2];
#pragma unroll
    for (int bb = 0; bb < 4; ++bb) {
        acc[bb][0] = make_float2(0.f, 0.f);
        acc[bb][1] = make_float2(0.f, 0.f);
    }
    const float4* Wb = W + (size_t)(6 * l + 3 * ih + s) * 4096 + dp;
    float4 cur[4];
#pragma unroll
    for (int j = 0; j < 4; ++j) cur[j] = Wb[(size_t)j * 64];
    for (int g = 0; g < 16; ++g) {
        float4 nxt[4];
        if (g < 15) {
#pragma unroll
            for (int j = 0; j < 4; ++j)
                nxt[j] = Wb[(size_t)((g + 1) * 4 + j) * 64];
        }
#pragma unroll
        for (int j = 0; j < 4; ++j) {
            int iu = ih * 64 + g * 4 + j;
            float2 wr = make_float2(cur[j].x, cur[j].y);
            float2 wi = make_float2(cur[j].z, cur[j].w);
#pragma unroll
            for (int bb = 0; bb < 4; ++bb) {
                float2 cv = cs[bb][iu];
                acc[bb][0].x += cv.x * wr.x - cv.y * wi.x;
                acc[bb][0].y += cv.x * wi.x + cv.y * wr.x;
                acc[bb][1].x += cv.x * wr.y - cv.y * wi.y;
                acc[bb][1].y += cv.x * wi.y + cv.y * wr.y;
            }
        }
        if (g < 15) {
#pragma unroll
            for (int j = 0; j < 4; ++j) cur[j] = nxt[j];
        }
    }
    if (ih == 1) {
#pragma unroll
        for (int bb = 0; bb < 4; ++bb) {
            red[r][bb][0] = acc[bb][0];
            red[r][bb][1] = acc[bb][1];
        }
    }
    __syncthreads();
    if (ih == 0) {
#pragma unroll
        for (int bb = 0; bb < 4; ++bb) {
            float2 r0 = red[r][bb][0];
            float2 r1 = red[r][bb][1];
            size_t o = ((size_t)(b0 + bb) * 256 + k) * 384 + s * 128 + 2 * dp;
            nts_h2(&oc[o], __float22half2_rn(
                make_float2(acc[bb][0].x + r0.x, acc[bb][0].y + r0.y)));
            nts_h2(&oc[o + 1], __float22half2_rn(
                make_float2(acc[bb][1].x + r1.x, acc[bb][1].y + r1.y)));
        }
    }
}

// K4: theta expansion + stats. oc loads nt; G stores nt; atomics unchanged.
__global__ __launch_bounds__(192, 4) void k_theta_out(const __half2* __restrict__ oc,
                                                      const float* __restrict__ A_out,
                                                      __half2* __restrict__ G,
                                                      float* __restrict__ ssr,
                                                      float* __restrict__ ssi,
                                                      float* __restrict__ ssq) {
    __shared__ float Ao[3][16][32];  // 6KB
    int mi = blockIdx.x, b = blockIdx.y, z = blockIdx.z;
    int m = mi - 15;
    int am = m < 0 ? -m : m;
    int tid = threadIdx.x;
    for (int idx = tid; idx < 1536; idx += 192) {
        int s = idx >> 9, j = (idx >> 5) & 15, t = idx & 31;
        float v = 0.f;
        if (j >= am) v = A_out[((size_t)s * 256 + (j * j + j + m)) * 32 + t];
        Ao[s][j][t] = v;
    }
    __syncthreads();
    int sd = z * 192 + tid;
    int s = sd >> 7;
    float2 c[16];
#pragma unroll
    for (int j = 0; j < 16; ++j) {
        c[j] = make_float2(0.f, 0.f);
        if (j >= am)
            c[j] = __half22float2(
                ntl_h2(&oc[((size_t)b * 256 + (j * j + j + m)) * 384 + sd]));
    }
    float sq = 0.f, sr = 0.f, si = 0.f;
    for (int t = 0; t < 32; ++t) {
        float fr = 0.f, fi = 0.f;
#pragma unroll
        for (int j = 0; j < 16; ++j) {
            float a = Ao[s][j][t];
            fr += a * c[j].x;
            fi += a * c[j].y;
        }
        nts_h2(&G[(((size_t)b * 32 + t) * 31 + mi) * 384 + sd],
               __float22half2_rn(make_float2(fr, fi)));
        sq += fr * fr + fi * fi;
        if (mi == 15) { sr += fr; si += fi; }
    }
    atomicAdd(&ssq[sd], sq);
    if (mi == 15) {
        atomicAdd(&ssr[sd], sr);
        atomicAdd(&ssi[sd], si);
    }
}

// K5: phi synthesis + BN + gate. G loads nt; out stores nt.
__global__ __launch_bounds__(192, 2) void k_synth_final(const __half2* __restrict__ G,
                                                        const float* __restrict__ ssr,
                                                        const float* __restrict__ ssi,
                                                        const float* __restrict__ ssq,
                                                        const float* __restrict__ gamma,
                                                        const float* __restrict__ betar,
                                                        const float* __restrict__ betai,
                                                        const float* __restrict__ bias,
                                                        float* __restrict__ out) {
    int bt = blockIdx.x;
    int sd = blockIdx.y * 192 + threadIdx.x;
    int s = sd >> 7;
    float2 g[31], st[31];
#pragma unroll
    for (int mi = 0; mi < 31; ++mi) {
        g[mi] = __half22float2(ntl_h2(&G[((size_t)bt * 31 + mi) * 384 + sd]));
        float sy, sx;
        __sincosf((float)(mi - 15) * (float)(PI_D / 16.0), &sy, &sx);
        st[mi] = make_float2(sx, sy);
    }
    const float invN = 1.0f / 256.0f;
    float mur = 0.f, mui = 0.f;
    if (s == 0) { mur = ssr[sd] * invN; mui = ssi[sd] * invN; }
    float var = ssq[sd] * invN - (mur * mur + mui * mui);
    float scale = gamma[sd] / sqrtf(var + 1e-5f);
    float br = (s == 0) ? betar[sd] : 0.f;
    float bi = (s == 0) ? betai[sd] : 0.f;
    float bb = bias[sd];
    float* ob = out + (size_t)bt * 32 * 384 + sd;
    for (int p = 0; p < 16; ++p) {
        float fr = 0.f, fi = 0.f, fr2 = 0.f, fi2 = 0.f;
#pragma unroll
        for (int mi = 0; mi < 31; ++mi) {
            fr += g[mi].x;
            fi += g[mi].y;
            if (mi & 1) { fr2 += g[mi].x; fi2 += g[mi].y; }  // m even
            else        { fr2 -= g[mi].x; fi2 -= g[mi].y; }  // m odd
        }
        {
            float yr = (fr - mur) * scale + br;
            float yi = (fi - mui) * scale + bi;
            float mag = sqrtf(yr * yr + yi * yi);
            float f = fmaxf(mag + bb, 0.f) / (mag + 1e-6f);
            nts_f(&ob[(size_t)p * 384], yr * f);
        }
        {
            float yr = (fr2 - mur) * scale + br;
            float yi = (fi2 - mui) * scale + bi;
            float mag = sqrtf(yr * yr + yi * yi);
            float f = fmaxf(mag + bb, 0.f) / (mag + 1e-6f);
            nts_f(&ob[(size_t)(p + 16) * 384], yr * f);
        }
#pragma unroll
        for (int mi = 0; mi < 31; ++mi) {
            float nx = g[mi].x * st[mi].x - g[mi].y * st[mi].y;
            g[mi].y = g[mi].x * st[mi].y + g[mi].y * st[mi].x;
            g[mi].x = nx;
        }
    }
}

extern "C" void kernel_launch(void* const* d_in, const int* in_sizes, int n_in,
                              void* d_out, int out_size, void* d_ws, size_t ws_size,
                              hipStream_t stream) {
    const float* xr    = (const float*)d_in[0];
    const float* xi    = (const float*)d_in[1];
    const float* kr    = (const float*)d_in[2];
    const float* ki    = (const float*)d_in[3];
    const float* gamma = (const float*)d_in[4];
    const float* betar = (const float*)d_in[5];
    const float* betai = (const float*)d_in[6];
    const float* bias  = (const float*)d_in[7];
    float* out = (float*)d_out;

    char* ws = (char*)d_ws;
    float*   A_in   = (float*)(ws + OFF_A_IN);
    float*   A_out  = (float*)(ws + OFF_A_OUT);
    float*   stats  = (float*)(ws + OFF_STATS);
    float*   ssr    = stats;
    float*   ssi    = stats + 384;
    float*   ssq    = stats + 768;
    __half2* F      = (__half2*)(ws + OFF_R1);  // then oc (fp16)
    __half2* oc     = (__half2*)(ws + OFF_R1);
    __half2* coeffs = (__half2*)(ws + OFF_R2);  // then G (fp16)
    __half2* G      = (__half2*)(ws + OFF_R2);
    float4*  W      = (float4*)(ws + OFF_W);

    k_phi_tables<<<675, 512, 0, stream>>>(xr, xi, F, A_in, A_out, stats, kr, ki, W);
    k_theta_in<<<dim3(31, 8, 2), 256, 0, stream>>>(F, A_in, coeffs);
    k_mix<<<dim3(256, 2), 384, 0, stream>>>(coeffs, W, oc);
    k_theta_out<<<dim3(31, 8, 2), 192, 0, stream>>>(oc, A_out, G, ssr, ssi, ssq);
    k_synth_final<<<dim3(256, 2), 192, 0, stream>>>(G, ssr, ssi, ssq,
                                                    gamma, betar, betai, bias, out);
}